// Round 1
// baseline (391.926 us; speedup 1.0000x reference)
//
#include <hip/hip_runtime.h>
#include <stdint.h>

#define E_TOTAL 100000
#define B_TOTAL 8
#define CIN 32
#define COUT 64

typedef short bf16x8 __attribute__((ext_vector_type(8)));
typedef float f32x4 __attribute__((ext_vector_type(4)));

union U16x8 { uint4 u; bf16x8 s; };

// ---- bf16 pair helpers (2 bf16 packed in one uint) ----
__device__ inline float blo(unsigned u) { return __uint_as_float(u << 16); }
__device__ inline float bhi(unsigned u) { return __uint_as_float(u & 0xffff0000u); }
// truncating pack (RTZ-ish): plenty of precision for 0.16 absmax budget
__device__ inline unsigned bpack(float lo, float hi) {
    return (__float_as_uint(lo) >> 16) | (__float_as_uint(hi) & 0xffff0000u);
}
__device__ inline unsigned badd(unsigned a, unsigned b) {
    return bpack(blo(a) + blo(b), bhi(a) + bhi(b));
}
__device__ inline unsigned babsdiff(unsigned a, unsigned b) {
    return bpack(fabsf(blo(a) - blo(b)), fabsf(bhi(a) - bhi(b)));
}
__device__ inline uint4 vadd(uint4 a, uint4 b) {
    uint4 r; r.x = badd(a.x, b.x); r.y = badd(a.y, b.y);
    r.z = badd(a.z, b.z); r.w = badd(a.w, b.w); return r;
}
__device__ inline uint4 vabsdiff(uint4 a, uint4 b) {
    uint4 r; r.x = babsdiff(a.x, b.x); r.y = babsdiff(a.y, b.y);
    r.z = babsdiff(a.z, b.z); r.w = babsdiff(a.w, b.w); return r;
}
// round-to-nearest-even fp32 -> bf16 (for the one-time converts)
__device__ inline unsigned rne16(float f) {
    unsigned b = __float_as_uint(f);
    b += 0x7fffu + ((b >> 16) & 1u);
    return b >> 16;
}

// ---- kernel 1: x (B,C,E) fp32 -> xt (B,E,32) bf16, LDS transpose ----
__global__ __launch_bounds__(256) void transpose_cast(
    const float* __restrict__ x, unsigned* __restrict__ xt /* as uint pairs */) {
    __shared__ float t[CIN][65];
    const int tid = threadIdx.x;
    const int b = blockIdx.x & 7;            // batch -> XCD affinity
    const int e0 = (blockIdx.x >> 3) * 64;
    const int el = tid & 63;
    const int cw = tid >> 6;                 // 0..3
#pragma unroll
    for (int i = 0; i < 8; i++) {
        int c = cw * 8 + i;
        int e = e0 + el;
        float v = (e < E_TOTAL) ? x[((size_t)b * CIN + c) * E_TOTAL + e] : 0.f;
        t[c][el] = v;
    }
    __syncthreads();
    const int c2 = tid & 15;                 // which bf16-pair (16 pairs = 32 ch)
#pragma unroll
    for (int i = 0; i < 4; i++) {
        int el2 = (tid >> 4) * 4 + i;
        int e = e0 + el2;
        if (e < E_TOTAL) {
            unsigned lo = rne16(t[c2 * 2][el2]);
            unsigned hi = rne16(t[c2 * 2 + 1][el2]);
            xt[((size_t)b * E_TOTAL + e) * 16 + c2] = lo | (hi << 16);
        }
    }
}

// ---- kernel 2: repack weight (64,32,1,5) fp32 into B-fragment-ready bf16 ----
// consumed as ((uint4*)wb)[(t*5+g)*64 + lane]; element j of lane (n=lane&15,q=lane>>4)
// = W[o = n+16t][c = q*8+j][g]
__global__ void wprep(const float* __restrict__ w, unsigned short* __restrict__ wb) {
    for (int idx = threadIdx.x; idx < 4 * 5 * 64 * 8; idx += 256) {
        int j = idx & 7;
        int lane = (idx >> 3) & 63;
        int tg = idx >> 9;          // t*5+g
        int g = tg % 5;
        int t = tg / 5;
        int n = lane & 15, q = lane >> 4;
        int o = n + 16 * t;
        int c = q * 8 + j;
        wb[idx] = (unsigned short)rne16(w[(o * CIN + c) * 5 + g]);
    }
}

// ---- kernel 3: gather + symmetric functions + MFMA GEMM ----
__global__ __launch_bounds__(256) void meshconv_main(
    const unsigned short* __restrict__ xt,   // (B,E,32) bf16
    const int* __restrict__ ge,              // (B,E,4)
    const unsigned short* __restrict__ wb,   // frag-ready weights
    const float* __restrict__ bias,          // (64)
    float* __restrict__ out) {               // (B,64,E) fp32
    const int lane = threadIdx.x & 63;
    const int wv = threadIdx.x >> 6;
    const int b = blockIdx.x & 7;            // batch -> XCD affinity
    const int tile = blockIdx.x >> 3;
    const int e0 = tile * 64 + wv * 16;
    if (e0 >= E_TOTAL) return;
    const int n = lane & 15;                 // A: edge row m ; B/D: o-within-tile
    const int q = lane >> 4;

    // loop-invariant weight fragments: 20 x uint4 = 80 VGPRs
    uint4 wfrag[4][5];
#pragma unroll
    for (int t = 0; t < 4; t++)
#pragma unroll
        for (int g = 0; g < 5; g++)
            wfrag[t][g] = ((const uint4*)wb)[(t * 5 + g) * 64 + lane];

    int em = e0 + n;
    if (em >= E_TOTAL) em = E_TOTAL - 1;     // E%16==0 so never taken; safety
    const int4 nid = *(const int4*)(ge + ((size_t)b * E_TOTAL + em) * 4);
    const unsigned short* xb = xt + (size_t)b * E_TOTAL * CIN;
    const int co = q * 8;
    uint4 a0 = *(const uint4*)(xb + (size_t)em * CIN + co);
    uint4 a1 = *(const uint4*)(xb + (size_t)nid.x * CIN + co);
    uint4 a2 = *(const uint4*)(xb + (size_t)nid.y * CIN + co);
    uint4 a3 = *(const uint4*)(xb + (size_t)nid.z * CIN + co);
    uint4 a4 = *(const uint4*)(xb + (size_t)nid.w * CIN + co);

    uint4 A[5];
    A[0] = a0;
    A[1] = vadd(a1, a3);        // f1+f3
    A[2] = vadd(a2, a4);        // f2+f4
    A[3] = vabsdiff(a1, a3);    // |f1-f3|
    A[4] = vabsdiff(a2, a4);    // |f2-f4|

    f32x4 acc[4];
#pragma unroll
    for (int t = 0; t < 4; t++)
#pragma unroll
        for (int r = 0; r < 4; r++) acc[t][r] = 0.f;

#pragma unroll
    for (int g = 0; g < 5; g++) {
        U16x8 av; av.u = A[g];
#pragma unroll
        for (int t = 0; t < 4; t++) {
            U16x8 bv; bv.u = wfrag[t][g];
            acc[t] = __builtin_amdgcn_mfma_f32_16x16x32_bf16(av.s, bv.s, acc[t], 0, 0, 0);
        }
    }

    // D layout: col(o) = lane&15, row(edge) = q*4 + reg
#pragma unroll
    for (int t = 0; t < 4; t++) {
        const int o = n + 16 * t;
        const float bv = bias[o];
        const int ebase = e0 + q * 4;
        float* orow = out + ((size_t)b * COUT + o) * E_TOTAL;
#pragma unroll
        for (int r = 0; r < 4; r++) {
            int e = ebase + r;
            if (e < E_TOTAL) orow[e] = acc[t][r] + bv;
        }
    }
}

// ---- fallback (no scratch needed): direct fp32, slow but correct ----
__global__ __launch_bounds__(256) void meshconv_fallback(
    const float* __restrict__ x, const int* __restrict__ ge,
    const float* __restrict__ w, const float* __restrict__ bias,
    float* __restrict__ out) {
    __shared__ float f[5][32];
    __shared__ float G[5][32];
    __shared__ int idxs[4];
    const int e = blockIdx.x, b = blockIdx.y;
    const int tid = threadIdx.x;
    if (tid < 4) idxs[tid] = ge[((size_t)b * E_TOTAL + e) * 4 + tid];
    __syncthreads();
    if (tid < 160) {
        int k = tid >> 5, c = tid & 31;
        int src = (k == 0) ? e : idxs[k - 1];
        f[k][c] = x[((size_t)b * CIN + c) * E_TOTAL + src];
    }
    __syncthreads();
    if (tid < 32) {
        int c = tid;
        G[0][c] = f[0][c];
        G[1][c] = f[1][c] + f[3][c];
        G[2][c] = f[2][c] + f[4][c];
        G[3][c] = fabsf(f[1][c] - f[3][c]);
        G[4][c] = fabsf(f[2][c] - f[4][c]);
    }
    __syncthreads();
    if (tid < COUT) {
        float acc = bias[tid];
        for (int c = 0; c < CIN; c++)
#pragma unroll
            for (int g = 0; g < 5; g++)
                acc += G[g][c] * w[(tid * CIN + c) * 5 + g];
        out[((size_t)b * COUT + tid) * E_TOTAL + e] = acc;
    }
}

extern "C" void kernel_launch(void* const* d_in, const int* in_sizes, int n_in,
                              void* d_out, int out_size, void* d_ws, size_t ws_size,
                              hipStream_t stream) {
    const float* x = (const float*)d_in[0];
    const int* ge = (const int*)d_in[1];
    const float* w = (const float*)d_in[2];
    const float* bias = (const float*)d_in[3];
    float* out = (float*)d_out;

    const size_t xt_bytes = (size_t)B_TOTAL * E_TOTAL * CIN * 2;  // 51.2 MB
    const size_t need = 65536 + xt_bytes;
    if (ws_size < need) {
        dim3 grid(E_TOTAL, B_TOTAL);
        meshconv_fallback<<<grid, 256, 0, stream>>>(x, ge, w, bias, out);
        return;
    }
    unsigned short* wb = (unsigned short*)d_ws;
    unsigned short* xt = (unsigned short*)((char*)d_ws + 65536);
    const int tiles = (E_TOTAL + 63) / 64;  // 1563

    wprep<<<1, 256, 0, stream>>>(w, wb);
    transpose_cast<<<tiles * 8, 256, 0, stream>>>(x, (unsigned*)xt);
    meshconv_main<<<tiles * 8, 256, 0, stream>>>(xt, ge, wb, bias, out);
}